// Round 19
// baseline (918.673 us; speedup 1.0000x reference)
//
#include <hip/hip_runtime.h>
#include <hip/hip_bf16.h>

typedef __attribute__((ext_vector_type(8))) short s8_t;    // 8 x bf16 (4 VGPR)
typedef __attribute__((ext_vector_type(4))) float f4_t;    // MFMA accumulator

// ---------- helpers ----------
__device__ __forceinline__ unsigned short f2bf(float f) {
  union { float f; unsigned u; } x; x.f = f;
  unsigned r = x.u + 0x7fffu + ((x.u >> 16) & 1u);  // RNE
  return (unsigned short)(r >> 16);
}

// truncation split, elementwise: hi = top16(v), lo = top16(v - hi)
__device__ __forceinline__ void split1(float v, unsigned short& h, unsigned short& l) {
  unsigned b = __float_as_uint(v);
  unsigned hb = b & 0xFFFF0000u;
  h = (unsigned short)(b >> 16);
  float lo = v - __uint_as_float(hb);
  l = (unsigned short)(__float_as_uint(lo) >> 16);
}

// pair split, packed (bit-identical per element to split1)
__device__ __forceinline__ void split2(float e0, float e1, unsigned& hp, unsigned& lp) {
  unsigned b0 = __float_as_uint(e0), b1 = __float_as_uint(e1);
  unsigned h0 = b0 & 0xFFFF0000u, h1 = b1 & 0xFFFF0000u;
  hp = (b0 >> 16) | h1;
  float l0 = e0 - __uint_as_float(h0), l1 = e1 - __uint_as_float(h1);
  lp = (__float_as_uint(l0) >> 16) | (__float_as_uint(l1) & 0xFFFF0000u);
}

__device__ __forceinline__ void gload16(const void* g, void* l) {
  __builtin_amdgcn_global_load_lds(
      (const __attribute__((address_space(1))) void*)g,
      (__attribute__((address_space(3))) void*)l, 16, 0, 0);
}

// T1 XCD swizzle (nwg % 8 == 0 for all grids using this)
__device__ __forceinline__ void swz_grid(int& bx, int& by, int& bz) {
  const int gx = gridDim.x, gy = gridDim.y;
  const int nwg = gx * gy * gridDim.z;
  const int flat = (blockIdx.z * gy + blockIdx.y) * gx + blockIdx.x;
  const int s = (flat & 7) * (nwg >> 3) + (flat >> 3);
  bx = s % gx;
  const int r = s / gx;
  by = r % gy;
  bz = r / gy;
}

// ---------- fp32 -> bf16 convert (Wv) ----------
__global__ __launch_bounds__(256) void k_convert(const float* __restrict__ in,
                                                 unsigned short* __restrict__ out, int n) {
  int i = (blockIdx.x * 256 + threadIdx.x) * 8;
  if (i >= n) return;
  float4 a = *(const float4*)(in + i);
  float4 b = *(const float4*)(in + i + 4);
  ushort4 u0; u0.x = f2bf(a.x); u0.y = f2bf(a.y); u0.z = f2bf(a.z); u0.w = f2bf(a.w);
  ushort4 u1; u1.x = f2bf(b.x); u1.y = f2bf(b.y); u1.z = f2bf(b.z); u1.w = f2bf(b.w);
  *(ushort4*)(out + i) = u0;
  *(ushort4*)(out + i + 4) = u1;
}

// ---------- FUSED x,y -> TRANSPOSED hi/lo bf16 planes (one launch, bz<32 -> x) ----------
__global__ __launch_bounds__(256) void k_tsplit2(const float* __restrict__ xx,
                                                 const float* __restrict__ yy,
                                                 unsigned short* __restrict__ xh,
                                                 unsigned short* __restrict__ xl,
                                                 unsigned short* __restrict__ yh,
                                                 unsigned short* __restrict__ yl) {
  __shared__ float tile[64][65];
  const int t = threadIdx.x;
  int bz = blockIdx.z;
  const float* in;
  unsigned short* th;
  unsigned short* tl;
  if (bz < 32) { in = xx; th = xh; tl = xl; }
  else         { bz -= 32; in = yy; th = yh; tl = yl; }
  const int r0 = blockIdx.y * 64, c0 = blockIdx.x * 64;
  const float* ip = in + (size_t)bz * 1048576;
  const size_t ob = (size_t)bz * 1048576;
  const int tr = t >> 4, tc = (t & 15) * 4;
#pragma unroll
  for (int p = 0; p < 4; ++p) {
    int r = p * 16 + tr;
    float4 v = *(const float4*)(ip + (size_t)(r0 + r) * 1024 + c0 + tc);
    tile[r][tc] = v.x; tile[r][tc + 1] = v.y; tile[r][tc + 2] = v.z; tile[r][tc + 3] = v.w;
  }
  __syncthreads();
#pragma unroll
  for (int p = 0; p < 4; ++p) {
    int n = p * 16 + tr;
    float a = tile[tc][n], b = tile[tc + 1][n], c = tile[tc + 2][n], d = tile[tc + 3][n];
    ushort4 h, l;
    split1(a, h.x, l.x); split1(b, h.y, l.y); split1(c, h.z, l.z); split1(d, h.w, l.w);
    *(ushort4*)(th + ob + (size_t)(c0 + n) * 1024 + r0 + tc) = h;
    *(ushort4*)(tl + ob + (size_t)(c0 + n) * 1024 + r0 + tc) = l;
  }
}

// ---------- fp32 [1024][1024]/batch -> bf16 transposed (for z) ----------
__global__ __launch_bounds__(256) void k_transpbf(const float* __restrict__ in,
                                                  unsigned short* __restrict__ outt) {
  __shared__ unsigned short tile[64][72];
  const int t = threadIdx.x, b = blockIdx.z;
  const int r0 = blockIdx.y * 64, c0 = blockIdx.x * 64;
  const float* ip = in + (size_t)b * 1048576;
  const int tr = t >> 4, tc = (t & 15) * 4;
#pragma unroll
  for (int p = 0; p < 4; ++p) {
    int r = p * 16 + tr;
    float4 v = *(const float4*)(ip + (size_t)(r0 + r) * 1024 + c0 + tc);
    tile[r][tc] = f2bf(v.x); tile[r][tc + 1] = f2bf(v.y);
    tile[r][tc + 2] = f2bf(v.z); tile[r][tc + 3] = f2bf(v.w);
  }
  __syncthreads();
#pragma unroll
  for (int p = 0; p < 4; ++p) {
    int n = p * 16 + tr;
    ushort4 w;
    w.x = tile[tc][n]; w.y = tile[tc + 1][n]; w.z = tile[tc + 2][n]; w.w = tile[tc + 3][n];
    *(ushort4*)(outt + (size_t)b * 1048576 + (size_t)(c0 + n) * 1024 + r0 + tc) = w;
  }
}

// split + write one 32-fp32 stripe (16 A + 16 B) into the 4 planes of buf,
// bank-swizzled: the two 16B slots land at w0, w1 (precomputed s^((row>>1)&3)).
__device__ __forceinline__ void split_write_swz(unsigned short* buf, int w0, int w1,
                                                const float* av, const float* bv) {
  unsigned ah[8], al[8], bh[8], bl[8];
#pragma unroll
  for (int p = 0; p < 8; ++p) {
    split2(av[2 * p], av[2 * p + 1], ah[p], al[p]);
    split2(bv[2 * p], bv[2 * p + 1], bh[p], bl[p]);
  }
  *(uint4*)(buf + w0) = *(uint4*)(ah);
  *(uint4*)(buf + w1) = *(uint4*)(ah + 4);
  *(uint4*)(buf + 4096 + w0) = *(uint4*)(al);
  *(uint4*)(buf + 4096 + w1) = *(uint4*)(al + 4);
  *(uint4*)(buf + 8192 + w0) = *(uint4*)(bh);
  *(uint4*)(buf + 8192 + w1) = *(uint4*)(bh + 4);
  *(uint4*)(buf + 12288 + w0) = *(uint4*)(bl);
  *(uint4*)(buf + 12288 + w1) = *(uint4*)(bl + 4);
}

// ---------- FUSED es+ec split-bf16 3-term MFMA GEMM (r12 body, 0 conflicts) ----------
// grid (8,8,64): swizzled bz<32 -> es (A=x,B=y,K=1024); bz>=32 -> ec
// (A=q_t,B=k_t,K=128). Independent outputs; co-residency lets short ec blocks
// backfill es's barrier-stall cycles (m114 cross-block overlap), removing the
// 40us serial ec launch. Math/order identical to the separate launches.
__global__ __launch_bounds__(256) void k_mfma3f(
    const float* __restrict__ Ax, const float* __restrict__ By,
    float* __restrict__ Ces,
    const float* __restrict__ Aq, const float* __restrict__ Bk,
    float* __restrict__ Cec) {
  __shared__ __align__(16) unsigned short sm[16384];  // Ah Al Bh Bl planes
  int bxs, bys, bz; swz_grid(bxs, bys, bz);
  const float* A; const float* B; float* C;
  int lda, ldc, K; long long sA, sC;
  if (bz < 32) {
    A = Ax; B = By; C = Ces; lda = 1024; ldc = 1024; K = 1024;
    sA = 1048576LL; sC = 1048576LL;
  } else {
    bz -= 32;
    A = Aq; B = Bk; C = Cec; lda = 128; ldc = 1024; K = 128;
    sA = 131072LL; sC = 1048576LL;
  }
  const int tid = threadIdx.x;
  const int lane = tid & 63, wave = tid >> 6;
  const int wr = wave >> 1, wc = wave & 1;
  const int m0 = bxs * 128, n0 = bys * 128;

  const int sr = tid >> 1, sh = (tid & 1) * 16;     // row, k-offset (fp32 elems)
  const float* ag = A + (long long)bz * sA + (long long)(m0 + sr) * lda + sh;
  const float* bg = B + (long long)bz * sA + (long long)(n0 + sr) * lda + sh;
  const int swm = (sr >> 1) & 3;
  const int s0 = (tid & 1) * 2;
  const int w0 = sr * 32 + (s0 ^ swm) * 8;
  const int w1 = sr * 32 + ((s0 + 1) ^ swm) * 8;

  const int lr = lane & 15, lg = lane >> 4;
  const int rdm = (lr >> 1) & 3;
  const int fa = (wr * 64 + lr) * 32 + (lg ^ rdm) * 8;
  const int fb = (wc * 64 + lr) * 32 + (lg ^ rdm) * 8;

  f4_t acc[4][4];
#pragma unroll
  for (int i = 0; i < 4; ++i)
#pragma unroll
    for (int j = 0; j < 4; ++j) acc[i][j] = (f4_t)0.f;

  for (int k0 = 0; k0 < K; k0 += 32) {
    float av[16], bv[16];
#pragma unroll
    for (int p = 0; p < 4; ++p) {
      *(float4*)(av + p * 4) = *(const float4*)(ag + p * 4);
      *(float4*)(bv + p * 4) = *(const float4*)(bg + p * 4);
    }
    split_write_swz(sm, w0, w1, av, bv);
    ag += 32; bg += 32;
    __syncthreads();
    const unsigned short* Ahp = sm;
    const unsigned short* Alp = sm + 4096;
    const unsigned short* Bhp = sm + 8192;
    const unsigned short* Blp = sm + 12288;
    s8_t fah[4], fbh[4], ftmp[4];
#pragma unroll
    for (int f = 0; f < 4; ++f) {
      fah[f] = *(const s8_t*)(Ahp + fa + f * 512);
      fbh[f] = *(const s8_t*)(Bhp + fb + f * 512);
    }
#pragma unroll
    for (int i = 0; i < 4; ++i)
#pragma unroll
      for (int j = 0; j < 4; ++j)
        acc[i][j] = __builtin_amdgcn_mfma_f32_16x16x32_bf16(fah[i], fbh[j], acc[i][j], 0, 0, 0);
#pragma unroll
    for (int f = 0; f < 4; ++f) ftmp[f] = *(const s8_t*)(Blp + fb + f * 512);
#pragma unroll
    for (int i = 0; i < 4; ++i)
#pragma unroll
      for (int j = 0; j < 4; ++j)
        acc[i][j] = __builtin_amdgcn_mfma_f32_16x16x32_bf16(fah[i], ftmp[j], acc[i][j], 0, 0, 0);
#pragma unroll
    for (int f = 0; f < 4; ++f) ftmp[f] = *(const s8_t*)(Alp + fa + f * 512);
#pragma unroll
    for (int i = 0; i < 4; ++i)
#pragma unroll
      for (int j = 0; j < 4; ++j)
        acc[i][j] = __builtin_amdgcn_mfma_f32_16x16x32_bf16(ftmp[i], fbh[j], acc[i][j], 0, 0, 0);
    __syncthreads();
  }

#pragma unroll
  for (int i = 0; i < 4; ++i) {
    const int rbase = m0 + wr * 64 + i * 16 + lg * 4;
#pragma unroll
    for (int j = 0; j < 4; ++j) {
      const int col = n0 + wc * 64 + j * 16 + lr;
#pragma unroll
      for (int e = 0; e < 4; ++e)
        C[(long long)bz * sC + (long long)(rbase + e) * ldc + col] = acc[i][j][e];
    }
  }
}

// ---------- merged q/k projection, PIPELINED + T2 swizzle (r12, validated) ----------
__global__ __launch_bounds__(256) void k_qk3p(
    const unsigned short* __restrict__ Axh, const unsigned short* __restrict__ Axl,
    const unsigned short* __restrict__ Ayh, const unsigned short* __restrict__ Ayl,
    const float* __restrict__ Wqf, const float* __restrict__ Wkf,
    const float* __restrict__ bqf, const float* __restrict__ bkf,
    float* __restrict__ Qt, float* __restrict__ Kt) {
  __shared__ __align__(16) unsigned short smAh[8192], smAl[8192];  // 2 bufs x 4096
  __shared__ __align__(16) unsigned short smBh[4096], smBl[4096];
  int bx, by, bz; swz_grid(bx, by, bz);
  const unsigned short* Ah = by ? Ayh : Axh;
  const unsigned short* Al = by ? Ayl : Axl;
  const float* Bf = by ? Wkf : Wqf;
  const float* bias = by ? bkf : bqf;
  float* Of = by ? Kt : Qt;

  const int tid = threadIdx.x, lane = tid & 63, wave = tid >> 6;
  const int wr = wave >> 1, wc = wave & 1;
  const int m0 = bx * 128;

  const int ch0 = wave * 64 + lane, ch1 = ch0 + 256;
  const int r0 = ch0 >> 2, kc0 = (((ch0 & 3) ^ ((ch0 >> 3) & 3))) * 8;
  const int r1 = ch1 >> 2, kc1 = (((ch1 & 3) ^ ((ch1 >> 3) & 3))) * 8;
  const unsigned short* pah0 = Ah + (long long)bz * 1048576 + (long long)(m0 + r0) * 1024 + kc0;
  const unsigned short* pah1 = Ah + (long long)bz * 1048576 + (long long)(m0 + r1) * 1024 + kc1;
  const unsigned short* pal0 = Al + (long long)bz * 1048576 + (long long)(m0 + r0) * 1024 + kc0;
  const unsigned short* pal1 = Al + (long long)bz * 1048576 + (long long)(m0 + r1) * 1024 + kc1;

  const int sr = tid >> 1, sh = (tid & 1) * 16;
  const float* bg = Bf + (long long)sr * 1024 + sh;
  const int swm = (sr >> 1) & 3;
  const int sB0 = (tid & 1) * 2;
  const int w0 = sr * 32 + (sB0 ^ swm) * 8;
  const int w1 = sr * 32 + ((sB0 + 1) ^ swm) * 8;

  const int lr = lane & 15, lg = lane >> 4;
  const int rdm = (lr >> 1) & 3;
  const int fa = (wr * 64 + lr) * 32 + (lg ^ rdm) * 8;
  const int fb = (wc * 64 + lr) * 32 + (lg ^ rdm) * 8;

  f4_t acc[4][4];
#pragma unroll
  for (int i = 0; i < 4; ++i)
#pragma unroll
    for (int j = 0; j < 4; ++j) acc[i][j] = (f4_t)0.f;

  float bv[16];
  auto stageA = [&](int b) {
    char* dh = (char*)smAh + b * 8192 + wave * 1024;
    char* dl = (char*)smAl + b * 8192 + wave * 1024;
    gload16(pah0, dh); gload16(pah1, dh + 4096);
    gload16(pal0, dl); gload16(pal1, dl + 4096);
    pah0 += 32; pah1 += 32; pal0 += 32; pal1 += 32;
  };
  auto loadW = [&]() {
#pragma unroll
    for (int p = 0; p < 4; ++p) *(float4*)(bv + p * 4) = *(const float4*)(bg + p * 4);
    bg += 32;
  };
  auto writeW = [&]() {
    unsigned bh[8], bl[8];
#pragma unroll
    for (int p = 0; p < 8; ++p) split2(bv[2 * p], bv[2 * p + 1], bh[p], bl[p]);
    *(uint4*)(smBh + w0) = *(uint4*)(bh);
    *(uint4*)(smBh + w1) = *(uint4*)(bh + 4);
    *(uint4*)(smBl + w0) = *(uint4*)(bl);
    *(uint4*)(smBl + w1) = *(uint4*)(bl + 4);
  };

  stageA(0);
  loadW();
  writeW();
  asm volatile("s_waitcnt vmcnt(0)" ::: "memory");
  __builtin_amdgcn_sched_barrier(0);
  __builtin_amdgcn_s_barrier();
  __builtin_amdgcn_sched_barrier(0);

  for (int t = 0; t < 32; ++t) {
    const bool more = (t < 31);
    if (more) { stageA((t + 1) & 1); loadW(); }
    const unsigned short* Ahp = smAh + (t & 1) * 4096;
    const unsigned short* Alp = smAl + (t & 1) * 4096;
    s8_t fah[4], fbh[4], ft[4];
#pragma unroll
    for (int f = 0; f < 4; ++f) {
      fah[f] = *(const s8_t*)(Ahp + fa + f * 512);
      fbh[f] = *(const s8_t*)(smBh + fb + f * 512);
    }
#pragma unroll
    for (int i = 0; i < 4; ++i)
#pragma unroll
      for (int j = 0; j < 4; ++j)
        acc[i][j] = __builtin_amdgcn_mfma_f32_16x16x32_bf16(fah[i], fbh[j], acc[i][j], 0, 0, 0);
#pragma unroll
    for (int f = 0; f < 4; ++f) ft[f] = *(const s8_t*)(smBl + fb + f * 512);
#pragma unroll
    for (int i = 0; i < 4; ++i)
#pragma unroll
      for (int j = 0; j < 4; ++j)
        acc[i][j] = __builtin_amdgcn_mfma_f32_16x16x32_bf16(fah[i], ft[j], acc[i][j], 0, 0, 0);
#pragma unroll
    for (int f = 0; f < 4; ++f) ft[f] = *(const s8_t*)(Alp + fa + f * 512);
#pragma unroll
    for (int i = 0; i < 4; ++i)
#pragma unroll
      for (int j = 0; j < 4; ++j)
        acc[i][j] = __builtin_amdgcn_mfma_f32_16x16x32_bf16(ft[i], fbh[j], acc[i][j], 0, 0, 0);
    __builtin_amdgcn_sched_barrier(0);
    __builtin_amdgcn_s_barrier();
    __builtin_amdgcn_sched_barrier(0);
    if (more) {
      writeW();
      asm volatile("s_waitcnt vmcnt(0)" ::: "memory");
    }
    __builtin_amdgcn_sched_barrier(0);
    __builtin_amdgcn_s_barrier();
    __builtin_amdgcn_sched_barrier(0);
  }

#pragma unroll
  for (int i = 0; i < 4; ++i) {
    const int rbase = m0 + wr * 64 + i * 16 + lg * 4;
#pragma unroll
    for (int j = 0; j < 4; ++j) {
      const int col = wc * 64 + j * 16 + lr;
      const float bc = bias[col];
#pragma unroll
      for (int e = 0; e < 4; ++e)
        Of[(long long)bz * 131072 + (long long)(rbase + e) * 128 + col] = acc[i][j][e] + bc;
    }
  }
}

// ---------- bf16 NT MFMA GEMM, 256x128 tile, 3-buf 72KB -> 2 blocks/CU (r14 proven) ----------
template <int BIAS_MODE, bool OUT_BF16, bool RESID>
__global__ __launch_bounds__(512, 4) void k_mfma256(
    const unsigned short* __restrict__ A, int lda, long long sA,
    const unsigned short* __restrict__ B, int ldb, long long sB,
    void* __restrict__ Cp, int ldc, long long sC,
    const float* __restrict__ bias,
    const float* __restrict__ resid, long long sR, int K) {
  __shared__ __align__(16) unsigned short As[24576];  // 3 bufs x 8192 shorts (256x32)
  __shared__ __align__(16) unsigned short Bs[12288];  // 3 bufs x 4096 shorts (128x32)
  int bxs, bys, bz; swz_grid(bxs, bys, bz);
  const int tid = threadIdx.x;
  const int lane = tid & 63, wave = tid >> 6;        // 8 waves
  const int wr = wave >> 1, wc = wave & 1;           // 4 x 2 -> wave tile 64x64
  const int m0 = bxs * 256, n0 = bys * 128;

  const int cA0 = tid, cA1 = tid + 512;
  const int ra0 = cA0 >> 2, sa0 = ((cA0 & 3) ^ ((cA0 >> 3) & 3)) * 8;
  const int ra1 = cA1 >> 2, sa1 = ((cA1 & 3) ^ ((cA1 >> 3) & 3)) * 8;
  const unsigned short* pa0 = A + (long long)bz * sA + (long long)(m0 + ra0) * lda + sa0;
  const unsigned short* pa1 = A + (long long)bz * sA + (long long)(m0 + ra1) * lda + sa1;
  const unsigned short* pb0 = B + (long long)bz * sB + (long long)(n0 + ra0) * ldb + sa0;

  const int lr = lane & 15, lg = lane >> 4;
  const int rdm = (lr >> 1) & 3;
  const int fa = (wr * 64 + lr) * 32 + (lg ^ rdm) * 8;
  const int fb = (wc * 64 + lr) * 32 + (lg ^ rdm) * 8;

  f4_t acc[4][4];
#pragma unroll
  for (int i = 0; i < 4; ++i)
#pragma unroll
    for (int j = 0; j < 4; ++j) acc[i][j] = (f4_t)0.f;

  unsigned short* a0 = As;        unsigned short* a1 = As + 8192;
  unsigned short* a2 = As + 16384;
  unsigned short* b0 = Bs;        unsigned short* b1 = Bs + 4096;
  unsigned short* b2 = Bs + 8192;

  auto gA0 = [&](unsigned short* la) { gload16(pa0, (char*)la + wave * 1024); pa0 += 32; };
  auto gA1 = [&](unsigned short* la) { gload16(pa1, (char*)la + 8192 + wave * 1024); pa1 += 32; };
  auto gB0 = [&](unsigned short* lb) { gload16(pb0, (char*)lb + wave * 1024); pb0 += 32; };

  const int nt = K >> 5;
  gA0(a0); gA1(a0); gB0(b0);
  gA0(a1); gA1(a1); gB0(b1);

  for (int t = 0; t < nt; ++t) {
    if (t < nt - 1) asm volatile("s_waitcnt vmcnt(3)" ::: "memory");
    else            asm volatile("s_waitcnt vmcnt(0)" ::: "memory");
    __builtin_amdgcn_sched_barrier(0);
    __builtin_amdgcn_s_barrier();
    __builtin_amdgcn_sched_barrier(0);
    const bool pf = (t + 2 < nt);
    const unsigned short* ap = a0;
    const unsigned short* bp = b0;
    s8_t af[4], bf[4];
    if (pf) gA0(a2);
#pragma unroll
    for (int j = 0; j < 4; ++j) bf[j] = *(const s8_t*)(bp + fb + j * 512);
    if (pf) gA1(a2);
#pragma unroll
    for (int i = 0; i < 4; ++i) af[i] = *(const s8_t*)(ap + fa + i * 512);
    if (pf) gB0(b2);
    __builtin_amdgcn_s_setprio(1);
#pragma unroll
    for (int i = 0; i < 4; ++i)
#pragma unroll
      for (int j = 0; j < 4; ++j)
        acc[i][j] = __builtin_amdgcn_mfma_f32_16x16x32_bf16(af[i], bf[j], acc[i][j], 0, 0, 0);
    __builtin_amdgcn_s_setprio(0);
    unsigned short* ta = a0; a0 = a1; a1 = a2; a2 = ta;
    unsigned short* tb = b0; b0 = b1; b1 = b2; b2 = tb;
  }

#pragma unroll
  for (int i = 0; i < 4; ++i) {
    const int rbase = m0 + wr * 64 + i * 16 + lg * 4;
#pragma unroll
    for (int j = 0; j < 4; ++j) {
      const int col = n0 + wc * 64 + j * 16 + lr;
#pragma unroll
      for (int e = 0; e < 4; ++e) {
        const int row = rbase + e;
        float v = acc[i][j][e];
        if (BIAS_MODE == 1) v += bias[row];
        const long long off = (long long)bz * sC + (long long)row * ldc + col;
        if (RESID) v += resid[(long long)bz * sR + (long long)row * ldc + col];
        if (OUT_BF16) ((unsigned short*)Cp)[off] = f2bf(v);
        else          ((float*)Cp)[off] = v;
      }
    }
  }
}

// ---------- fused triple softmax: ONE WAVE PER ROW ----------
__device__ __forceinline__ float wred_max(float v) {
#pragma unroll
  for (int o = 1; o < 64; o <<= 1) v = fmaxf(v, __shfl_xor(v, o, 64));
  return v;
}
__device__ __forceinline__ float wred_sum(float v) {
#pragma unroll
  for (int o = 1; o < 64; o <<= 1) v += __shfl_xor(v, o, 64);
  return v;
}

__global__ __launch_bounds__(256) void k_combine(float* __restrict__ ec,
                                                 const float* __restrict__ es) {
  const int lane = threadIdx.x & 63, wid = threadIdx.x >> 6;
  const size_t row = (size_t)blockIdx.x * 4 + wid;
  float* cp = ec + row * 1024;
  const float* sp = es + row * 1024;
  float4 c[4], s[4];
#pragma unroll
  for (int p = 0; p < 4; ++p) {
    c[p] = ((const float4*)cp)[lane * 4 + p];
    s[p] = ((const float4*)sp)[lane * 4 + p];
  }
  float mx = -3.4e38f;
#pragma unroll
  for (int p = 0; p < 4; ++p)
    mx = fmaxf(mx, fmaxf(fmaxf(c[p].x, c[p].y), fmaxf(c[p].z, c[p].w)));
  mx = wred_max(mx);
  float e[16], lsum = 0.f;
#pragma unroll
  for (int p = 0; p < 4; ++p) {
    e[4 * p]     = __expf(c[p].x - mx);
    e[4 * p + 1] = __expf(c[p].y - mx);
    e[4 * p + 2] = __expf(c[p].z - mx);
    e[4 * p + 3] = __expf(c[p].w - mx);
    lsum += e[4 * p] + e[4 * p + 1] + e[4 * p + 2] + e[4 * p + 3];
  }
  const float sc = wred_sum(lsum);
  float mt = -3.4e38f;
#pragma unroll
  for (int p = 0; p < 4; ++p)
    mt = fmaxf(mt, fmaxf(fmaxf(-s[p].x, -s[p].y), fmaxf(-s[p].z, -s[p].w)));
  mt = wred_max(mt);
  float f[16]; lsum = 0.f;
#pragma unroll
  for (int p = 0; p < 4; ++p) {
    f[4 * p]     = __expf(-s[p].x - mt);
    f[4 * p + 1] = __expf(-s[p].y - mt);
    f[4 * p + 2] = __expf(-s[p].z - mt);
    f[4 * p + 3] = __expf(-s[p].w - mt);
    lsum += f[4 * p] + f[4 * p + 1] + f[4 * p + 2] + f[4 * p + 3];
  }
  const float ss = wred_sum(lsum);
  const float rc = 1.f / sc, rs = 1.f / ss;
  float g[16]; lsum = 0.f;
#pragma unroll
  for (int q = 0; q < 16; ++q) {
    g[q] = __expf((e[q] * rc) * (f[q] * rs));
    lsum += g[q];
  }
  const float s3 = wred_sum(lsum);
  const float r3 = 1.f / s3;
#pragma unroll
  for (int p = 0; p < 4; ++p) {
    ushort4 o;
    o.x = f2bf(g[4 * p] * r3);     o.y = f2bf(g[4 * p + 1] * r3);
    o.z = f2bf(g[4 * p + 2] * r3); o.w = f2bf(g[4 * p + 3] * r3);
    ((ushort4*)cp)[lane * 4 + p] = o;
  }
}

// ---------- launch ----------
extern "C" void kernel_launch(void* const* d_in, const int* in_sizes, int n_in,
                              void* d_out, int out_size, void* d_ws, size_t ws_size,
                              hipStream_t stream) {
  const float* z = (const float*)d_in[0];
  const float* x = (const float*)d_in[1];
  const float* y = (const float*)d_in[2];
  const float* Wq = (const float*)d_in[3];
  const float* bq = (const float*)d_in[4];
  const float* Wk = (const float*)d_in[5];
  const float* bk = (const float*)d_in[6];
  const float* Wv = (const float*)d_in[7];
  const float* bv = (const float*)d_in[8];
  float* out = (float*)d_out;

  // ws (288 MiB):
  // P01 [0,128M):   y^T hi/lo planes -> es fp32 -> z_t bf16 [0,64M) | v_bf [64M,128M)
  // P23 [128,256M): x^T hi/lo planes -> ec fp32 (attn bf16 in-place, row stride 2048)
  // P4  [256,288M): q_t fp32 16M | k_t fp32 16M -> wv bf16 2M
  char* ws = (char*)d_ws;
  unsigned short* yth = (unsigned short*)ws;
  unsigned short* ytl = yth + 33554432;
  float* es = (float*)ws;
  unsigned short* z_t = (unsigned short*)ws;
  unsigned short* v_bf = z_t + 33554432;
  char* wsB = ws + 134217728;
  unsigned short* xth = (unsigned short*)wsB;
  unsigned short* xtl = xth + 33554432;
  float* ec = (float*)wsB;
  unsigned short* attn = (unsigned short*)wsB;
  char* wsC = ws + 268435456;
  float* q_t = (float*)wsC;            // [32][1024][128]
  float* k_t = q_t + 4194304;
  unsigned short* wv = (unsigned short*)wsC;

  dim3 blk(256);
  // fused x/y transpose+split (one launch)
  hipLaunchKernelGGL(k_tsplit2, dim3(16, 16, 64), blk, 0, stream, x, y, xth, xtl, yth, ytl);
  hipLaunchKernelGGL(k_qk3p, dim3(8, 2, 32), blk, 0, stream,
                     xth, xtl, yth, ytl, Wq, Wk, bq, bk, q_t, k_t);
  // fused es + ec (independent GEMMs co-resident; ec backfills es stalls)
  hipLaunchKernelGGL(k_mfma3f, dim3(8, 8, 64), blk, 0, stream,
                     x, y, es, q_t, k_t, ec);
  hipLaunchKernelGGL(k_combine, dim3(8192), blk, 0, stream, ec, es);
  hipLaunchKernelGGL(k_transpbf, dim3(16, 16, 32), blk, 0, stream, z, z_t);
  hipLaunchKernelGGL(k_convert, dim3(512), blk, 0, stream, Wv, wv, 1048576);
  hipLaunchKernelGGL((k_mfma256<1, true, false>), dim3(4, 8, 32), dim3(512), 0, stream,
                     wv, 1024, 0LL, z_t, 1024, 1048576LL, (void*)v_bf, 1024, 1048576LL,
                     bv, (const float*)nullptr, 0LL, 1024);
  hipLaunchKernelGGL((k_mfma256<0, false, true>), dim3(4, 8, 32), dim3(512), 0, stream,
                     v_bf, 1024, 1048576LL, attn, 2048, 2097152LL, (void*)out, 1024, 1048576LL,
                     (const float*)nullptr, z, 1048576LL, 1024);
}

// Round 20
// 743.705 us; speedup vs baseline: 1.2353x; 1.2353x over previous
//
#include <hip/hip_runtime.h>
#include <hip/hip_bf16.h>

typedef __attribute__((ext_vector_type(8))) short s8_t;    // 8 x bf16 (4 VGPR)
typedef __attribute__((ext_vector_type(4))) float f4_t;    // MFMA accumulator

// ---------- helpers ----------
__device__ __forceinline__ unsigned short f2bf(float f) {
  union { float f; unsigned u; } x; x.f = f;
  unsigned r = x.u + 0x7fffu + ((x.u >> 16) & 1u);  // RNE
  return (unsigned short)(r >> 16);
}

// truncation split, elementwise: hi = top16(v), lo = top16(v - hi)
__device__ __forceinline__ void split1(float v, unsigned short& h, unsigned short& l) {
  unsigned b = __float_as_uint(v);
  unsigned hb = b & 0xFFFF0000u;
  h = (unsigned short)(b >> 16);
  float lo = v - __uint_as_float(hb);
  l = (unsigned short)(__float_as_uint(lo) >> 16);
}

// pair split, packed (bit-identical per element to split1)
__device__ __forceinline__ void split2(float e0, float e1, unsigned& hp, unsigned& lp) {
  unsigned b0 = __float_as_uint(e0), b1 = __float_as_uint(e1);
  unsigned h0 = b0 & 0xFFFF0000u, h1 = b1 & 0xFFFF0000u;
  hp = (b0 >> 16) | h1;
  float l0 = e0 - __uint_as_float(h0), l1 = e1 - __uint_as_float(h1);
  lp = (__float_as_uint(l0) >> 16) | (__float_as_uint(l1) & 0xFFFF0000u);
}

__device__ __forceinline__ void gload16(const void* g, void* l) {
  __builtin_amdgcn_global_load_lds(
      (const __attribute__((address_space(1))) void*)g,
      (__attribute__((address_space(3))) void*)l, 16, 0, 0);
}

// T1 XCD swizzle (nwg % 8 == 0 for all grids using this)
__device__ __forceinline__ void swz_grid(int& bx, int& by, int& bz) {
  const int gx = gridDim.x, gy = gridDim.y;
  const int nwg = gx * gy * gridDim.z;
  const int flat = (blockIdx.z * gy + blockIdx.y) * gx + blockIdx.x;
  const int s = (flat & 7) * (nwg >> 3) + (flat >> 3);
  bx = s % gx;
  const int r = s / gx;
  by = r % gy;
  bz = r / gy;
}

// ---------- fp32 -> bf16 convert (Wv) ----------
__global__ __launch_bounds__(256) void k_convert(const float* __restrict__ in,
                                                 unsigned short* __restrict__ out, int n) {
  int i = (blockIdx.x * 256 + threadIdx.x) * 8;
  if (i >= n) return;
  float4 a = *(const float4*)(in + i);
  float4 b = *(const float4*)(in + i + 4);
  ushort4 u0; u0.x = f2bf(a.x); u0.y = f2bf(a.y); u0.z = f2bf(a.z); u0.w = f2bf(a.w);
  ushort4 u1; u1.x = f2bf(b.x); u1.y = f2bf(b.y); u1.z = f2bf(b.z); u1.w = f2bf(b.w);
  *(ushort4*)(out + i) = u0;
  *(ushort4*)(out + i + 4) = u1;
}

// ---------- FUSED x,y -> TRANSPOSED hi/lo bf16 planes (one launch) ----------
// bz parity interleave: even -> x slice bz/2, odd -> y slice bz/2 (balanced per XCD).
__global__ __launch_bounds__(256) void k_tsplit2(const float* __restrict__ xx,
                                                 const float* __restrict__ yy,
                                                 unsigned short* __restrict__ xh,
                                                 unsigned short* __restrict__ xl,
                                                 unsigned short* __restrict__ yh,
                                                 unsigned short* __restrict__ yl) {
  __shared__ float tile[64][65];
  const int t = threadIdx.x;
  int L = blockIdx.z;
  const float* in;
  unsigned short* th;
  unsigned short* tl;
  const int bz = L >> 1;
  if ((L & 1) == 0) { in = xx; th = xh; tl = xl; }
  else              { in = yy; th = yh; tl = yl; }
  const int r0 = blockIdx.y * 64, c0 = blockIdx.x * 64;
  const float* ip = in + (size_t)bz * 1048576;
  const size_t ob = (size_t)bz * 1048576;
  const int tr = t >> 4, tc = (t & 15) * 4;
#pragma unroll
  for (int p = 0; p < 4; ++p) {
    int r = p * 16 + tr;
    float4 v = *(const float4*)(ip + (size_t)(r0 + r) * 1024 + c0 + tc);
    tile[r][tc] = v.x; tile[r][tc + 1] = v.y; tile[r][tc + 2] = v.z; tile[r][tc + 3] = v.w;
  }
  __syncthreads();
#pragma unroll
  for (int p = 0; p < 4; ++p) {
    int n = p * 16 + tr;
    float a = tile[tc][n], b = tile[tc + 1][n], c = tile[tc + 2][n], d = tile[tc + 3][n];
    ushort4 h, l;
    split1(a, h.x, l.x); split1(b, h.y, l.y); split1(c, h.z, l.z); split1(d, h.w, l.w);
    *(ushort4*)(th + ob + (size_t)(c0 + n) * 1024 + r0 + tc) = h;
    *(ushort4*)(tl + ob + (size_t)(c0 + n) * 1024 + r0 + tc) = l;
  }
}

// ---------- fp32 [1024][1024]/batch -> bf16 transposed (for z) ----------
__global__ __launch_bounds__(256) void k_transpbf(const float* __restrict__ in,
                                                  unsigned short* __restrict__ outt) {
  __shared__ unsigned short tile[64][72];
  const int t = threadIdx.x, b = blockIdx.z;
  const int r0 = blockIdx.y * 64, c0 = blockIdx.x * 64;
  const float* ip = in + (size_t)b * 1048576;
  const int tr = t >> 4, tc = (t & 15) * 4;
#pragma unroll
  for (int p = 0; p < 4; ++p) {
    int r = p * 16 + tr;
    float4 v = *(const float4*)(ip + (size_t)(r0 + r) * 1024 + c0 + tc);
    tile[r][tc] = f2bf(v.x); tile[r][tc + 1] = f2bf(v.y);
    tile[r][tc + 2] = f2bf(v.z); tile[r][tc + 3] = f2bf(v.w);
  }
  __syncthreads();
#pragma unroll
  for (int p = 0; p < 4; ++p) {
    int n = p * 16 + tr;
    ushort4 w;
    w.x = tile[tc][n]; w.y = tile[tc + 1][n]; w.z = tile[tc + 2][n]; w.w = tile[tc + 3][n];
    *(ushort4*)(outt + (size_t)b * 1048576 + (size_t)(c0 + n) * 1024 + r0 + tc) = w;
  }
}

// split + write one 32-fp32 stripe (16 A + 16 B) into the 4 planes of buf,
// bank-swizzled: the two 16B slots land at w0, w1 (precomputed s^((row>>1)&3)).
__device__ __forceinline__ void split_write_swz(unsigned short* buf, int w0, int w1,
                                                const float* av, const float* bv) {
  unsigned ah[8], al[8], bh[8], bl[8];
#pragma unroll
  for (int p = 0; p < 8; ++p) {
    split2(av[2 * p], av[2 * p + 1], ah[p], al[p]);
    split2(bv[2 * p], bv[2 * p + 1], bh[p], bl[p]);
  }
  *(uint4*)(buf + w0) = *(uint4*)(ah);
  *(uint4*)(buf + w1) = *(uint4*)(ah + 4);
  *(uint4*)(buf + 4096 + w0) = *(uint4*)(al);
  *(uint4*)(buf + 4096 + w1) = *(uint4*)(al + 4);
  *(uint4*)(buf + 8192 + w0) = *(uint4*)(bh);
  *(uint4*)(buf + 8192 + w1) = *(uint4*)(bh + 4);
  *(uint4*)(buf + 12288 + w0) = *(uint4*)(bl);
  *(uint4*)(buf + 12288 + w1) = *(uint4*)(bl + 4);
}

// ---------- FUSED es+ec split-bf16 3-term MFMA GEMM (r12 body, 0 conflicts) ----------
// grid (8,8,64). Logical slice L = swizzled bz: L even -> es batch L/2
// (A=x,B=y,K=1024); L odd -> ec batch L/2 (A=q_t,B=k_t,K=128). Parity interleave
// puts 4 es + 4 ec batches in每 XCD chunk -> balanced; ec's short blocks backfill
// es's barrier stalls (m114). Math identical to the separate launches.
__global__ __launch_bounds__(256) void k_mfma3f(
    const float* __restrict__ Ax, const float* __restrict__ By,
    float* __restrict__ Ces,
    const float* __restrict__ Aq, const float* __restrict__ Bk,
    float* __restrict__ Cec) {
  __shared__ __align__(16) unsigned short sm[16384];  // Ah Al Bh Bl planes
  int bxs, bys, L; swz_grid(bxs, bys, L);
  const float* A; const float* B; float* C;
  int lda, K; long long sA;
  const int bz = L >> 1;
  if ((L & 1) == 0) {
    A = Ax; B = By; C = Ces; lda = 1024; K = 1024; sA = 1048576LL;
  } else {
    A = Aq; B = Bk; C = Cec; lda = 128; K = 128; sA = 131072LL;
  }
  const int tid = threadIdx.x;
  const int lane = tid & 63, wave = tid >> 6;
  const int wr = wave >> 1, wc = wave & 1;
  const int m0 = bxs * 128, n0 = bys * 128;

  const int sr = tid >> 1, sh = (tid & 1) * 16;     // row, k-offset (fp32 elems)
  const float* ag = A + (long long)bz * sA + (long long)(m0 + sr) * lda + sh;
  const float* bg = B + (long long)bz * sA + (long long)(n0 + sr) * lda + sh;
  const int swm = (sr >> 1) & 3;
  const int s0 = (tid & 1) * 2;
  const int w0 = sr * 32 + (s0 ^ swm) * 8;
  const int w1 = sr * 32 + ((s0 + 1) ^ swm) * 8;

  const int lr = lane & 15, lg = lane >> 4;
  const int rdm = (lr >> 1) & 3;
  const int fa = (wr * 64 + lr) * 32 + (lg ^ rdm) * 8;
  const int fb = (wc * 64 + lr) * 32 + (lg ^ rdm) * 8;

  f4_t acc[4][4];
#pragma unroll
  for (int i = 0; i < 4; ++i)
#pragma unroll
    for (int j = 0; j < 4; ++j) acc[i][j] = (f4_t)0.f;

  for (int k0 = 0; k0 < K; k0 += 32) {
    float av[16], bv[16];
#pragma unroll
    for (int p = 0; p < 4; ++p) {
      *(float4*)(av + p * 4) = *(const float4*)(ag + p * 4);
      *(float4*)(bv + p * 4) = *(const float4*)(bg + p * 4);
    }
    split_write_swz(sm, w0, w1, av, bv);
    ag += 32; bg += 32;
    __syncthreads();
    const unsigned short* Ahp = sm;
    const unsigned short* Alp = sm + 4096;
    const unsigned short* Bhp = sm + 8192;
    const unsigned short* Blp = sm + 12288;
    s8_t fah[4], fbh[4], ftmp[4];
#pragma unroll
    for (int f = 0; f < 4; ++f) {
      fah[f] = *(const s8_t*)(Ahp + fa + f * 512);
      fbh[f] = *(const s8_t*)(Bhp + fb + f * 512);
    }
#pragma unroll
    for (int i = 0; i < 4; ++i)
#pragma unroll
      for (int j = 0; j < 4; ++j)
        acc[i][j] = __builtin_amdgcn_mfma_f32_16x16x32_bf16(fah[i], fbh[j], acc[i][j], 0, 0, 0);
#pragma unroll
    for (int f = 0; f < 4; ++f) ftmp[f] = *(const s8_t*)(Blp + fb + f * 512);
#pragma unroll
    for (int i = 0; i < 4; ++i)
#pragma unroll
      for (int j = 0; j < 4; ++j)
        acc[i][j] = __builtin_amdgcn_mfma_f32_16x16x32_bf16(fah[i], ftmp[j], acc[i][j], 0, 0, 0);
#pragma unroll
    for (int f = 0; f < 4; ++f) ftmp[f] = *(const s8_t*)(Alp + fa + f * 512);
#pragma unroll
    for (int i = 0; i < 4; ++i)
#pragma unroll
      for (int j = 0; j < 4; ++j)
        acc[i][j] = __builtin_amdgcn_mfma_f32_16x16x32_bf16(ftmp[i], fbh[j], acc[i][j], 0, 0, 0);
    __syncthreads();
  }

#pragma unroll
  for (int i = 0; i < 4; ++i) {
    const int rbase = m0 + wr * 64 + i * 16 + lg * 4;
#pragma unroll
    for (int j = 0; j < 4; ++j) {
      const int col = n0 + wc * 64 + j * 16 + lr;
#pragma unroll
      for (int e = 0; e < 4; ++e)
        C[(long long)bz * 1048576LL + (long long)(rbase + e) * 1024 + col] = acc[i][j][e];
    }
  }
}

// ---------- merged q/k projection, PIPELINED + T2 swizzle (r12, validated) ----------
__global__ __launch_bounds__(256) void k_qk3p(
    const unsigned short* __restrict__ Axh, const unsigned short* __restrict__ Axl,
    const unsigned short* __restrict__ Ayh, const unsigned short* __restrict__ Ayl,
    const float* __restrict__ Wqf, const float* __restrict__ Wkf,
    const float* __restrict__ bqf, const float* __restrict__ bkf,
    float* __restrict__ Qt, float* __restrict__ Kt) {
  __shared__ __align__(16) unsigned short smAh[8192], smAl[8192];  // 2 bufs x 4096
  __shared__ __align__(16) unsigned short smBh[4096], smBl[4096];
  int bx, by, bz; swz_grid(bx, by, bz);
  const unsigned short* Ah = by ? Ayh : Axh;
  const unsigned short* Al = by ? Ayl : Axl;
  const float* Bf = by ? Wkf : Wqf;
  const float* bias = by ? bkf : bqf;
  float* Of = by ? Kt : Qt;

  const int tid = threadIdx.x, lane = tid & 63, wave = tid >> 6;
  const int wr = wave >> 1, wc = wave & 1;
  const int m0 = bx * 128;

  const int ch0 = wave * 64 + lane, ch1 = ch0 + 256;
  const int r0 = ch0 >> 2, kc0 = (((ch0 & 3) ^ ((ch0 >> 3) & 3))) * 8;
  const int r1 = ch1 >> 2, kc1 = (((ch1 & 3) ^ ((ch1 >> 3) & 3))) * 8;
  const unsigned short* pah0 = Ah + (long long)bz * 1048576 + (long long)(m0 + r0) * 1024 + kc0;
  const unsigned short* pah1 = Ah + (long long)bz * 1048576 + (long long)(m0 + r1) * 1024 + kc1;
  const unsigned short* pal0 = Al + (long long)bz * 1048576 + (long long)(m0 + r0) * 1024 + kc0;
  const unsigned short* pal1 = Al + (long long)bz * 1048576 + (long long)(m0 + r1) * 1024 + kc1;

  const int sr = tid >> 1, sh = (tid & 1) * 16;
  const float* bg = Bf + (long long)sr * 1024 + sh;
  const int swm = (sr >> 1) & 3;
  const int sB0 = (tid & 1) * 2;
  const int w0 = sr * 32 + (sB0 ^ swm) * 8;
  const int w1 = sr * 32 + ((sB0 + 1) ^ swm) * 8;

  const int lr = lane & 15, lg = lane >> 4;
  const int rdm = (lr >> 1) & 3;
  const int fa = (wr * 64 + lr) * 32 + (lg ^ rdm) * 8;
  const int fb = (wc * 64 + lr) * 32 + (lg ^ rdm) * 8;

  f4_t acc[4][4];
#pragma unroll
  for (int i = 0; i < 4; ++i)
#pragma unroll
    for (int j = 0; j < 4; ++j) acc[i][j] = (f4_t)0.f;

  float bv[16];
  auto stageA = [&](int b) {
    char* dh = (char*)smAh + b * 8192 + wave * 1024;
    char* dl = (char*)smAl + b * 8192 + wave * 1024;
    gload16(pah0, dh); gload16(pah1, dh + 4096);
    gload16(pal0, dl); gload16(pal1, dl + 4096);
    pah0 += 32; pah1 += 32; pal0 += 32; pal1 += 32;
  };
  auto loadW = [&]() {
#pragma unroll
    for (int p = 0; p < 4; ++p) *(float4*)(bv + p * 4) = *(const float4*)(bg + p * 4);
    bg += 32;
  };
  auto writeW = [&]() {
    unsigned bh[8], bl[8];
#pragma unroll
    for (int p = 0; p < 8; ++p) split2(bv[2 * p], bv[2 * p + 1], bh[p], bl[p]);
    *(uint4*)(smBh + w0) = *(uint4*)(bh);
    *(uint4*)(smBh + w1) = *(uint4*)(bh + 4);
    *(uint4*)(smBl + w0) = *(uint4*)(bl);
    *(uint4*)(smBl + w1) = *(uint4*)(bl + 4);
  };

  stageA(0);
  loadW();
  writeW();
  asm volatile("s_waitcnt vmcnt(0)" ::: "memory");
  __builtin_amdgcn_sched_barrier(0);
  __builtin_amdgcn_s_barrier();
  __builtin_amdgcn_sched_barrier(0);

  for (int t = 0; t < 32; ++t) {
    const bool more = (t < 31);
    if (more) { stageA((t + 1) & 1); loadW(); }
    const unsigned short* Ahp = smAh + (t & 1) * 4096;
    const unsigned short* Alp = smAl + (t & 1) * 4096;
    s8_t fah[4], fbh[4], ft[4];
#pragma unroll
    for (int f = 0; f < 4; ++f) {
      fah[f] = *(const s8_t*)(Ahp + fa + f * 512);
      fbh[f] = *(const s8_t*)(smBh + fb + f * 512);
    }
#pragma unroll
    for (int i = 0; i < 4; ++i)
#pragma unroll
      for (int j = 0; j < 4; ++j)
        acc[i][j] = __builtin_amdgcn_mfma_f32_16x16x32_bf16(fah[i], fbh[j], acc[i][j], 0, 0, 0);
#pragma unroll
    for (int f = 0; f < 4; ++f) ft[f] = *(const s8_t*)(smBl + fb + f * 512);
#pragma unroll
    for (int i = 0; i < 4; ++i)
#pragma unroll
      for (int j = 0; j < 4; ++j)
        acc[i][j] = __builtin_amdgcn_mfma_f32_16x16x32_bf16(fah[i], ft[j], acc[i][j], 0, 0, 0);
#pragma unroll
    for (int f = 0; f < 4; ++f) ft[f] = *(const s8_t*)(Alp + fa + f * 512);
#pragma unroll
    for (int i = 0; i < 4; ++i)
#pragma unroll
      for (int j = 0; j < 4; ++j)
        acc[i][j] = __builtin_amdgcn_mfma_f32_16x16x32_bf16(ft[i], fbh[j], acc[i][j], 0, 0, 0);
    __builtin_amdgcn_sched_barrier(0);
    __builtin_amdgcn_s_barrier();
    __builtin_amdgcn_sched_barrier(0);
    if (more) {
      writeW();
      asm volatile("s_waitcnt vmcnt(0)" ::: "memory");
    }
    __builtin_amdgcn_sched_barrier(0);
    __builtin_amdgcn_s_barrier();
    __builtin_amdgcn_sched_barrier(0);
  }

#pragma unroll
  for (int i = 0; i < 4; ++i) {
    const int rbase = m0 + wr * 64 + i * 16 + lg * 4;
#pragma unroll
    for (int j = 0; j < 4; ++j) {
      const int col = wc * 64 + j * 16 + lr;
      const float bc = bias[col];
#pragma unroll
      for (int e = 0; e < 4; ++e)
        Of[(long long)bz * 131072 + (long long)(rbase + e) * 128 + col] = acc[i][j][e] + bc;
    }
  }
}

// ---------- bf16 NT MFMA GEMM, 256x128 tile, 3-buf 72KB -> 2 blocks/CU (r14 proven) ----------
template <int BIAS_MODE, bool OUT_BF16, bool RESID>
__global__ __launch_bounds__(512, 4) void k_mfma256(
    const unsigned short* __restrict__ A, int lda, long long sA,
    const unsigned short* __restrict__ B, int ldb, long long sB,
    void* __restrict__ Cp, int ldc, long long sC,
    const float* __restrict__ bias,
    const float* __restrict__ resid, long long sR, int K) {
  __shared__ __align__(16) unsigned short As[24576];  // 3 bufs x 8192 shorts (256x32)
  __shared__ __align__(16) unsigned short Bs[12288];  // 3 bufs x 4096 shorts (128x32)
  int bxs, bys, bz; swz_grid(bxs, bys, bz);
  const int tid = threadIdx.x;
  const int lane = tid & 63, wave = tid >> 6;        // 8 waves
  const int wr = wave >> 1, wc = wave & 1;           // 4 x 2 -> wave tile 64x64
  const int m0 = bxs * 256, n0 = bys * 128;

  const int cA0 = tid, cA1 = tid + 512;
  const int ra0 = cA0 >> 2, sa0 = ((cA0 & 3) ^ ((cA0 >> 3) & 3)) * 8;
  const int ra1 = cA1 >> 2, sa1 = ((cA1 & 3) ^ ((cA1 >> 3) & 3)) * 8;
  const unsigned short* pa0 = A + (long long)bz * sA + (long long)(m0 + ra0) * lda + sa0;
  const unsigned short* pa1 = A + (long long)bz * sA + (long long)(m0 + ra1) * lda + sa1;
  const unsigned short* pb0 = B + (long long)bz * sB + (long long)(n0 + ra0) * ldb + sa0;

  const int lr = lane & 15, lg = lane >> 4;
  const int rdm = (lr >> 1) & 3;
  const int fa = (wr * 64 + lr) * 32 + (lg ^ rdm) * 8;
  const int fb = (wc * 64 + lr) * 32 + (lg ^ rdm) * 8;

  f4_t acc[4][4];
#pragma unroll
  for (int i = 0; i < 4; ++i)
#pragma unroll
    for (int j = 0; j < 4; ++j) acc[i][j] = (f4_t)0.f;

  unsigned short* a0 = As;        unsigned short* a1 = As + 8192;
  unsigned short* a2 = As + 16384;
  unsigned short* b0 = Bs;        unsigned short* b1 = Bs + 4096;
  unsigned short* b2 = Bs + 8192;

  auto gA0 = [&](unsigned short* la) { gload16(pa0, (char*)la + wave * 1024); pa0 += 32; };
  auto gA1 = [&](unsigned short* la) { gload16(pa1, (char*)la + 8192 + wave * 1024); pa1 += 32; };
  auto gB0 = [&](unsigned short* lb) { gload16(pb0, (char*)lb + wave * 1024); pb0 += 32; };

  const int nt = K >> 5;
  gA0(a0); gA1(a0); gB0(b0);
  gA0(a1); gA1(a1); gB0(b1);

  for (int t = 0; t < nt; ++t) {
    if (t < nt - 1) asm volatile("s_waitcnt vmcnt(3)" ::: "memory");
    else            asm volatile("s_waitcnt vmcnt(0)" ::: "memory");
    __builtin_amdgcn_sched_barrier(0);
    __builtin_amdgcn_s_barrier();
    __builtin_amdgcn_sched_barrier(0);
    const bool pf = (t + 2 < nt);
    const unsigned short* ap = a0;
    const unsigned short* bp = b0;
    s8_t af[4], bf[4];
    if (pf) gA0(a2);
#pragma unroll
    for (int j = 0; j < 4; ++j) bf[j] = *(const s8_t*)(bp + fb + j * 512);
    if (pf) gA1(a2);
#pragma unroll
    for (int i = 0; i < 4; ++i) af[i] = *(const s8_t*)(ap + fa + i * 512);
    if (pf) gB0(b2);
    __builtin_amdgcn_s_setprio(1);
#pragma unroll
    for (int i = 0; i < 4; ++i)
#pragma unroll
      for (int j = 0; j < 4; ++j)
        acc[i][j] = __builtin_amdgcn_mfma_f32_16x16x32_bf16(af[i], bf[j], acc[i][j], 0, 0, 0);
    __builtin_amdgcn_s_setprio(0);
    unsigned short* ta = a0; a0 = a1; a1 = a2; a2 = ta;
    unsigned short* tb = b0; b0 = b1; b1 = b2; b2 = tb;
  }

#pragma unroll
  for (int i = 0; i < 4; ++i) {
    const int rbase = m0 + wr * 64 + i * 16 + lg * 4;
#pragma unroll
    for (int j = 0; j < 4; ++j) {
      const int col = n0 + wc * 64 + j * 16 + lr;
#pragma unroll
      for (int e = 0; e < 4; ++e) {
        const int row = rbase + e;
        float v = acc[i][j][e];
        if (BIAS_MODE == 1) v += bias[row];
        const long long off = (long long)bz * sC + (long long)row * ldc + col;
        if (RESID) v += resid[(long long)bz * sR + (long long)row * ldc + col];
        if (OUT_BF16) ((unsigned short*)Cp)[off] = f2bf(v);
        else          ((float*)Cp)[off] = v;
      }
    }
  }
}

// ---------- fused triple softmax: ONE WAVE PER ROW ----------
__device__ __forceinline__ float wred_max(float v) {
#pragma unroll
  for (int o = 1; o < 64; o <<= 1) v = fmaxf(v, __shfl_xor(v, o, 64));
  return v;
}
__device__ __forceinline__ float wred_sum(float v) {
#pragma unroll
  for (int o = 1; o < 64; o <<= 1) v += __shfl_xor(v, o, 64);
  return v;
}

__global__ __launch_bounds__(256) void k_combine(float* __restrict__ ec,
                                                 const float* __restrict__ es) {
  const int lane = threadIdx.x & 63, wid = threadIdx.x >> 6;
  const size_t row = (size_t)blockIdx.x * 4 + wid;
  float* cp = ec + row * 1024;
  const float* sp = es + row * 1024;
  float4 c[4], s[4];
#pragma unroll
  for (int p = 0; p < 4; ++p) {
    c[p] = ((const float4*)cp)[lane * 4 + p];
    s[p] = ((const float4*)sp)[lane * 4 + p];
  }
  float mx = -3.4e38f;
#pragma unroll
  for (int p = 0; p < 4; ++p)
    mx = fmaxf(mx, fmaxf(fmaxf(c[p].x, c[p].y), fmaxf(c[p].z, c[p].w)));
  mx = wred_max(mx);
  float e[16], lsum = 0.f;
#pragma unroll
  for (int p = 0; p < 4; ++p) {
    e[4 * p]     = __expf(c[p].x - mx);
    e[4 * p + 1] = __expf(c[p].y - mx);
    e[4 * p + 2] = __expf(c[p].z - mx);
    e[4 * p + 3] = __expf(c[p].w - mx);
    lsum += e[4 * p] + e[4 * p + 1] + e[4 * p + 2] + e[4 * p + 3];
  }
  const float sc = wred_sum(lsum);
  float mt = -3.4e38f;
#pragma unroll
  for (int p = 0; p < 4; ++p)
    mt = fmaxf(mt, fmaxf(fmaxf(-s[p].x, -s[p].y), fmaxf(-s[p].z, -s[p].w)));
  mt = wred_max(mt);
  float f[16]; lsum = 0.f;
#pragma unroll
  for (int p = 0; p < 4; ++p) {
    f[4 * p]     = __expf(-s[p].x - mt);
    f[4 * p + 1] = __expf(-s[p].y - mt);
    f[4 * p + 2] = __expf(-s[p].z - mt);
    f[4 * p + 3] = __expf(-s[p].w - mt);
    lsum += f[4 * p] + f[4 * p + 1] + f[4 * p + 2] + f[4 * p + 3];
  }
  const float ss = wred_sum(lsum);
  const float rc = 1.f / sc, rs = 1.f / ss;
  float g[16]; lsum = 0.f;
#pragma unroll
  for (int q = 0; q < 16; ++q) {
    g[q] = __expf((e[q] * rc) * (f[q] * rs));
    lsum += g[q];
  }
  const float s3 = wred_sum(lsum);
  const float r3 = 1.f / s3;
#pragma unroll
  for (int p = 0; p < 4; ++p) {
    ushort4 o;
    o.x = f2bf(g[4 * p] * r3);     o.y = f2bf(g[4 * p + 1] * r3);
    o.z = f2bf(g[4 * p + 2] * r3); o.w = f2bf(g[4 * p + 3] * r3);
    ((ushort4*)cp)[lane * 4 + p] = o;
  }
}

// ---------- launch ----------
extern "C" void kernel_launch(void* const* d_in, const int* in_sizes, int n_in,
                              void* d_out, int out_size, void* d_ws, size_t ws_size,
                              hipStream_t stream) {
  const float* z = (const float*)d_in[0];
  const float* x = (const float*)d_in[1];
  const float* y = (const float*)d_in[2];
  const float* Wq = (const float*)d_in[3];
  const float* bq = (const float*)d_in[4];
  const float* Wk = (const float*)d_in[5];
  const float* bk = (const float*)d_in[6];
  const float* Wv = (const float*)d_in[7];
  const float* bv = (const float*)d_in[8];
  float* out = (float*)d_out;

  // ws (288 MiB):
  // P01 [0,128M):   y^T hi/lo planes -> es fp32 -> z_t bf16 [0,64M) | v_bf [64M,128M)
  // P23 [128,256M): x^T hi/lo planes -> ec fp32 (attn bf16 in-place, row stride 2048)
  // P4  [256,288M): q_t fp32 16M | k_t fp32 16M -> wv bf16 2M
  char* ws = (char*)d_ws;
  unsigned short* yth = (unsigned short*)ws;
  unsigned short* ytl = yth + 33554432;
  float* es = (float*)ws;
  unsigned short* z_t = (unsigned short*)ws;
  unsigned short* v_bf = z_t + 33554432;
  char* wsB = ws + 134217728;
  unsigned short* xth = (unsigned short*)wsB;
  unsigned short* xtl = xth + 33554432;
  float* ec = (float*)wsB;
  unsigned short* attn = (unsigned short*)wsB;
  char* wsC = ws + 268435456;
  float* q_t = (float*)wsC;            // [32][1024][128]
  float* k_t = q_t + 4194304;
  unsigned short* wv = (unsigned short*)wsC;

  dim3 blk(256);
  // fused x/y transpose+split (parity-interleaved z)
  hipLaunchKernelGGL(k_tsplit2, dim3(16, 16, 64), blk, 0, stream, x, y, xth, xtl, yth, ytl);
  hipLaunchKernelGGL(k_qk3p, dim3(8, 2, 32), blk, 0, stream,
                     xth, xtl, yth, ytl, Wq, Wk, bq, bk, q_t, k_t);
  // fused es + ec (parity-interleaved z -> balanced per XCD; ec backfills es stalls)
  hipLaunchKernelGGL(k_mfma3f, dim3(8, 8, 64), blk, 0, stream,
                     x, y, es, q_t, k_t, ec);
  hipLaunchKernelGGL(k_combine, dim3(8192), blk, 0, stream, ec, es);
  hipLaunchKernelGGL(k_transpbf, dim3(16, 16, 32), blk, 0, stream, z, z_t);
  hipLaunchKernelGGL(k_convert, dim3(512), blk, 0, stream, Wv, wv, 1048576);
  hipLaunchKernelGGL((k_mfma256<1, true, false>), dim3(4, 8, 32), dim3(512), 0, stream,
                     wv, 1024, 0LL, z_t, 1024, 1048576LL, (void*)v_bf, 1024, 1048576LL,
                     bv, (const float*)nullptr, 0LL, 1024);
  hipLaunchKernelGGL((k_mfma256<0, false, true>), dim3(4, 8, 32), dim3(512), 0, stream,
                     v_bf, 1024, 1048576LL, attn, 2048, 2097152LL, (void*)out, 1024, 1048576LL,
                     (const float*)nullptr, z, 1048576LL, 1024);
}